// Round 1
// baseline (2797.402 us; speedup 1.0000x reference)
//
#include <hip/hip_runtime.h>
#include <math.h>

// QuaternionAttention: B=4, L=S=2048, H=8, E=64, M=4, fp32.
// Flash-style streaming attention using the ABCD trig decomposition of the
// quaternion-rotated score (rank-4 in the 64-dim q/k dots + 4 trig dots),
// avoiding the M*E=256-dim rotated feature materialization entirely.

#define B_ 4
#define L_ 2048
#define S_ 2048
#define H_ 8
#define E_ 64
#define M_ 4
#define TQ 32
#define TK 32
#define NTHREADS 256

__device__ __forceinline__ float dot4(float4 a, float4 b) {
    return a.x*b.x + a.y*b.y + a.z*b.z + a.w*b.w;
}

__global__ __launch_bounds__(NTHREADS)
void qattn_flash_f32(const float* __restrict__ qp, const float* __restrict__ kp,
                     const float* __restrict__ vp,
                     const float* __restrict__ qo, const float* __restrict__ qt,
                     const float* __restrict__ ko, const float* __restrict__ kt,
                     float* __restrict__ out)
{
    const int l0 = blockIdx.x * TQ;
    const int h  = blockIdx.y;
    const int b  = blockIdx.z;
    const int t  = threadIdx.x;
    const int r  = t >> 3;   // query row within tile [0,32)
    const int c  = t & 7;    // sub-lane: key subset in score phase, e-chunk in PV

    // Row stride 68 (=64+4) floats: breaks power-of-2 bank aliasing across rows,
    // keeps 16B alignment (272 B) for float4 LDS ops.
    __shared__ __attribute__((aligned(16))) float qs[TQ][68];
    __shared__ __attribute__((aligned(16))) float qtr[TQ][8];   // cos[0..3], sin[0..3]
    __shared__ __attribute__((aligned(16))) float ks[TK][68];
    __shared__ __attribute__((aligned(16))) float ktr[TK][8];
    __shared__ __attribute__((aligned(16))) float vs[TK][68];
    __shared__ float ps[TQ][TK + 1];

    // ---- stage Q tile (rows l0..l0+31) ----
    for (int f = t; f < TQ * 16; f += NTHREADS) {
        int row = f >> 4, ch = f & 15;
        const float4 val = *(const float4*)(qp + (((size_t)(b * L_ + l0 + row) * H_ + h) * E_) + ch * 4);
        *(float4*)&qs[row][ch * 4] = val;
    }
    for (int idx = t; idx < TQ * M_; idx += NTHREADS) {
        int row = idx >> 2, m = idx & 3;
        size_t off = ((size_t)(b * L_ + l0 + row) * H_ + h) * M_ + m;
        float pos = (float)(l0 + row) * (1.0f / (float)L_);
        float a = qo[off] * pos + qt[off];
        qtr[row][m]     = __cosf(a);
        qtr[row][4 + m] = __sinf(a);
    }

    float4 acc0 = {0.f, 0.f, 0.f, 0.f}, acc1 = {0.f, 0.f, 0.f, 0.f};
    float mrow = -1e30f, lrow = 0.0f;

    for (int s0 = 0; s0 < S_; s0 += TK) {
        // ---- stage K, V tiles + key trig ----
        for (int f = t; f < TK * 16; f += NTHREADS) {
            int row = f >> 4, ch = f & 15;
            size_t base = (((size_t)(b * S_ + s0 + row) * H_ + h) * E_) + ch * 4;
            *(float4*)&ks[row][ch * 4] = *(const float4*)(kp + base);
            *(float4*)&vs[row][ch * 4] = *(const float4*)(vp + base);
        }
        for (int idx = t; idx < TK * M_; idx += NTHREADS) {
            int row = idx >> 2, m = idx & 3;
            size_t off = ((size_t)(b * S_ + s0 + row) * H_ + h) * M_ + m;
            float pos = (float)(s0 + row) * (1.0f / (float)S_);
            float a = ko[off] * pos + kt[off];
            ktr[row][m]     = __cosf(a);
            ktr[row][4 + m] = __sinf(a);
        }
        __syncthreads();

        // ---- scores: thread handles row r, keys j = jj*8 + c ----
        float Av[4] = {0,0,0,0}, Bv[4] = {0,0,0,0}, Cv[4] = {0,0,0,0}, Dv[4] = {0,0,0,0};
        #pragma unroll
        for (int e4 = 0; e4 < 4; ++e4) {
            float4 q0 = *(float4*)&qs[r][     e4 * 4];
            float4 q1 = *(float4*)&qs[r][16 + e4 * 4];
            float4 q2 = *(float4*)&qs[r][32 + e4 * 4];
            float4 q3 = *(float4*)&qs[r][48 + e4 * 4];
            #pragma unroll
            for (int jj = 0; jj < 4; ++jj) {
                int j = jj * 8 + c;
                float4 k0 = *(float4*)&ks[j][     e4 * 4];
                float4 k1 = *(float4*)&ks[j][16 + e4 * 4];
                float4 k2 = *(float4*)&ks[j][32 + e4 * 4];
                float4 k3 = *(float4*)&ks[j][48 + e4 * 4];
                Av[jj] += dot4(q0,k0) + dot4(q1,k1) + dot4(q2,k2) + dot4(q3,k3);
                Bv[jj] += dot4(q2,k0) + dot4(q3,k1) - dot4(q0,k2) - dot4(q1,k3);
                Cv[jj] += dot4(q0,k1) - dot4(q1,k0) + dot4(q3,k2) - dot4(q2,k3);
                Dv[jj] += dot4(q3,k0) - dot4(q2,k1) + dot4(q1,k2) - dot4(q0,k3);
            }
        }
        float4 qc  = *(float4*)&qtr[r][0];
        float4 qsn = *(float4*)&qtr[r][4];
        float sc[4];
        #pragma unroll
        for (int jj = 0; jj < 4; ++jj) {
            int j = jj * 8 + c;
            float4 kc  = *(float4*)&ktr[j][0];
            float4 ksn = *(float4*)&ktr[j][4];
            float CCv = dot4(qc, kc), CSv = dot4(qc, ksn);
            float SCv = dot4(qsn, kc), SSv = dot4(qsn, ksn);
            // logits = (1/M) * (1/sqrt(E)) * raw = raw / 32
            sc[jj] = (Av[jj]*CCv + Bv[jj]*CSv + Cv[jj]*SCv + Dv[jj]*SSv) * (1.0f / 32.0f);
        }

        // ---- online softmax across the row's 8 threads (lanes 8r..8r+7) ----
        float tm = fmaxf(fmaxf(sc[0], sc[1]), fmaxf(sc[2], sc[3]));
        tm = fmaxf(tm, __shfl_xor(tm, 1));
        tm = fmaxf(tm, __shfl_xor(tm, 2));
        tm = fmaxf(tm, __shfl_xor(tm, 4));
        float mnew  = fmaxf(mrow, tm);
        float alpha = __expf(mrow - mnew);
        float p0 = __expf(sc[0] - mnew), p1 = __expf(sc[1] - mnew);
        float p2 = __expf(sc[2] - mnew), p3 = __expf(sc[3] - mnew);
        float tsum = p0 + p1 + p2 + p3;
        tsum += __shfl_xor(tsum, 1);
        tsum += __shfl_xor(tsum, 2);
        tsum += __shfl_xor(tsum, 4);
        lrow = lrow * alpha + tsum;
        mrow = mnew;
        acc0.x *= alpha; acc0.y *= alpha; acc0.z *= alpha; acc0.w *= alpha;
        acc1.x *= alpha; acc1.y *= alpha; acc1.z *= alpha; acc1.w *= alpha;
        ps[r][ 0 + c] = p0;
        ps[r][ 8 + c] = p1;
        ps[r][16 + c] = p2;
        ps[r][24 + c] = p3;
        __syncthreads();

        // ---- PV: thread owns (row r, e-channels c*8..c*8+7) ----
        #pragma unroll 8
        for (int j = 0; j < TK; ++j) {
            float pj = ps[r][j];
            float4 v0 = *(float4*)&vs[j][c * 8];
            float4 v1 = *(float4*)&vs[j][c * 8 + 4];
            acc0.x += pj * v0.x; acc0.y += pj * v0.y; acc0.z += pj * v0.z; acc0.w += pj * v0.w;
            acc1.x += pj * v1.x; acc1.y += pj * v1.y; acc1.z += pj * v1.z; acc1.w += pj * v1.w;
        }
        __syncthreads();
    }

    float inv = 1.0f / lrow;
    float4 o0 = {acc0.x * inv, acc0.y * inv, acc0.z * inv, acc0.w * inv};
    float4 o1 = {acc1.x * inv, acc1.y * inv, acc1.z * inv, acc1.w * inv};
    float* op = out + (((size_t)(b * L_ + l0 + r) * H_ + h) * E_) + c * 8;
    *(float4*)op       = o0;
    *(float4*)(op + 4) = o1;
}

extern "C" void kernel_launch(void* const* d_in, const int* in_sizes, int n_in,
                              void* d_out, int out_size, void* d_ws, size_t ws_size,
                              hipStream_t stream) {
    const float* qp = (const float*)d_in[0];
    const float* kp = (const float*)d_in[1];
    const float* vp = (const float*)d_in[2];
    const float* qo = (const float*)d_in[3];
    const float* qt = (const float*)d_in[4];
    const float* ko = (const float*)d_in[5];
    const float* kt = (const float*)d_in[6];
    float* out = (float*)d_out;

    dim3 grid(L_ / TQ, H_, B_);
    qattn_flash_f32<<<grid, dim3(NTHREADS), 0, stream>>>(qp, kp, vp, qo, qt, ko, kt, out);
}

// Round 2
// 437.213 us; speedup vs baseline: 6.3983x; 6.3983x over previous
//
#include <hip/hip_runtime.h>
#include <math.h>

// QuaternionAttention B=4, L=S=2048, H=8, E=64, M=4 (fp32 in/out).
// MFMA flash attention via ABCD trig decomposition:
//   raw(l,s) = A*CC + B*CS + C*SC + D*SS,  logits = raw/32
// A/B/C/D are Q(64) x K4-variant GEMMs on fp16 MFMA; CC/CS/SC/SS are M=4
// trig dots on VALU. Online softmax in-lane; P round-trips LDS (wave-local)
// into A-layout for the PV MFMA. All hot LDS uses XOR-chunk swizzle
// (16B-chunk index ^= row&7) so b128 fragment reads span all 32 banks.

#define B_ 4
#define L_ 2048
#define S_ 2048
#define H_ 8
#define E_ 64
#define M_ 4
#define NTH 256

typedef _Float16 f16x4 __attribute__((ext_vector_type(4)));
typedef _Float16 f16x8 __attribute__((ext_vector_type(8)));
typedef float f32x4 __attribute__((ext_vector_type(4)));

union H4U { f16x4 h; unsigned int u[2]; };

__global__ __launch_bounds__(NTH)
void qattn_mfma(const float* __restrict__ qp, const float* __restrict__ kp,
                const float* __restrict__ vp,
                const float* __restrict__ qo, const float* __restrict__ qt,
                const float* __restrict__ ko, const float* __restrict__ ktt,
                float* __restrict__ out)
{
    const int l0 = blockIdx.x * 64;
    const int h  = blockIdx.y;
    const int b  = blockIdx.z;
    const int t  = threadIdx.x;
    const int wv   = t >> 6;   // wave id: owns rows wv*16 .. wv*16+15
    const int lane = t & 63;
    const int quad = lane >> 4;
    const int nn   = lane & 15;

    // fp16 tiles, rows of 64 halves (128 B) with XOR-chunk swizzle (no pad).
    __shared__ _Float16 k4s[4][64][64];  // [variant][key][e]
    __shared__ _Float16 vts[64][64];     // [e][key]  (V transposed)
    __shared__ _Float16 pss[64][64];     // [row][key]; Q staged here first
    __shared__ float ktrc[64][4], ktrs[64][4];
    __shared__ float qtrc[64][4], qtrs[64][4];

    // ---- stage Q (fp16, swizzled) + query trig ----
    {
        const float* qb = qp + ((size_t)((b * L_ + l0) * H_ + h)) * E_;
        #pragma unroll
        for (int i = 0; i < 4; ++i) {
            int idx = t + NTH * i;
            int row = idx >> 4, c16 = idx & 15;
            float4 v = *(const float4*)(qb + (size_t)row * (H_ * E_) + c16 * 4);
            f16x4 hq = { (_Float16)v.x, (_Float16)v.y, (_Float16)v.z, (_Float16)v.w };
            int k = c16 * 4;
            int ch = ((k >> 3) ^ (row & 7));
            *(f16x4*)&pss[row][ch * 8 + (k & 7)] = hq;
        }
        int row = t >> 2, m = t & 3;
        size_t off = (size_t)((b * L_ + l0 + row) * H_ + h) * M_ + m;
        float ang = qo[off] * ((float)(l0 + row) * (1.0f / L_)) + qt[off];
        qtrc[row][m] = __cosf(ang);
        qtrs[row][m] = __sinf(ang);
    }
    __syncthreads();

    // ---- Q A-frags (persistent) + per-row trig to registers ----
    f16x8 qfrag[2];
    {
        int arow = wv * 16 + nn;           // A-operand row = lane&15
        #pragma unroll
        for (int ks = 0; ks < 2; ++ks) {
            int ch = ((quad + 4 * ks) ^ (arow & 7));
            qfrag[ks] = *(f16x8*)&pss[arow][ch * 8];
        }
    }
    float4 qcv[4], qsv[4];                 // trig for C/D rows quad*4+r
    #pragma unroll
    for (int r = 0; r < 4; ++r) {
        int row = wv * 16 + quad * 4 + r;
        qcv[r] = *(float4*)&qtrc[row][0];
        qsv[r] = *(float4*)&qtrs[row][0];
    }
    __syncthreads();                       // pss now free for P

    f32x4 Oacc[4] = {{0,0,0,0},{0,0,0,0},{0,0,0,0},{0,0,0,0}};
    float mrow[4] = {-1e30f,-1e30f,-1e30f,-1e30f};
    float lrow[4] = {0.f,0.f,0.f,0.f};

    const float* kb0 = kp  + ((size_t)((b * S_) * H_ + h)) * E_;
    const float* vb0 = vp  + ((size_t)((b * S_) * H_ + h)) * E_;
    const float* kob = ko  + ((size_t)((b * S_) * H_ + h)) * M_;
    const float* ktb = ktt + ((size_t)((b * S_) * H_ + h)) * M_;

    for (int s0 = 0; s0 < S_; s0 += 64) {
        // ---- stage K as 4 sign/permute variants + V transposed (fp16) ----
        // variant columns (chunk = 16 e's):
        //  A: ( k0, k1, k2, k3)   B: (-k2,-k3, k0, k1)
        //  C: ( k1,-k0,-k3, k2)   D: (-k3, k2,-k1, k0)
        #pragma unroll
        for (int i = 0; i < 4; ++i) {
            int idx = t + NTH * i;
            int key = idx >> 4, c16 = idx & 15;
            size_t gbase = (size_t)(s0 + key) * (H_ * E_) + c16 * 4;
            float4 kv = *(const float4*)(kb0 + gbase);
            float4 vv = *(const float4*)(vb0 + gbase);
            H4U hk; hk.h = (f16x4){ (_Float16)kv.x, (_Float16)kv.y, (_Float16)kv.z, (_Float16)kv.w };
            int Ec  = c16 >> 2;            // source 16-chunk
            int ohi = (c16 >> 1) & 1;      // (offset>>3)
            int olo = (c16 & 1) * 4;       // offset&7
            const int dx[4] = {0, 2, 1, 3};                 // dest chunk = Ec ^ dx[v]
            const int ng[4] = {0, (Ec >> 1) & 1,
                               (Ec == 0 || Ec == 3) ? 1 : 0, Ec & 1};  // negate?
            #pragma unroll
            for (int v = 0; v < 4; ++v) {
                int d  = Ec ^ dx[v];
                int ch = ((d * 2 + ohi) ^ (key & 7));
                unsigned int msk = ng[v] ? 0x80008000u : 0u;
                H4U w; w.u[0] = hk.u[0] ^ msk; w.u[1] = hk.u[1] ^ msk;
                *(f16x4*)&k4s[v][key][ch * 8 + olo] = w.h;
            }
            float ve[4] = {vv.x, vv.y, vv.z, vv.w};
            #pragma unroll
            for (int j = 0; j < 4; ++j) {
                int e = c16 * 4 + j;
                int ch = ((key >> 3) ^ (e & 7));
                vts[e][ch * 8 + (key & 7)] = (_Float16)ve[j];
            }
        }
        {
            int key = t >> 2, m = t & 3;
            size_t off = (size_t)(s0 + key) * (H_ * M_) + m;
            float ang = kob[off] * ((float)(s0 + key) * (1.0f / S_)) + ktb[off];
            ktrc[key][m] = __cosf(ang);
            ktrs[key][m] = __sinf(ang);
        }
        __syncthreads();

        // ---- scores: this wave's 16 rows x 64 keys ----
        float sc[4][4];   // [key-tile][reg]; C/D: col=nn(key), row=quad*4+reg
        #pragma unroll
        for (int kt2 = 0; kt2 < 4; ++kt2) {
            int keyb = kt2 * 16 + nn;
            f32x4 accA = {0,0,0,0}, accB = {0,0,0,0}, accC = {0,0,0,0}, accD = {0,0,0,0};
            #pragma unroll
            for (int ks = 0; ks < 2; ++ks) {
                int ch = ((quad + 4 * ks) ^ (nn & 7)) * 8;
                f16x8 bA = *(f16x8*)&k4s[0][keyb][ch];
                f16x8 bB = *(f16x8*)&k4s[1][keyb][ch];
                f16x8 bC = *(f16x8*)&k4s[2][keyb][ch];
                f16x8 bD = *(f16x8*)&k4s[3][keyb][ch];
                accA = __builtin_amdgcn_mfma_f32_16x16x32_f16(qfrag[ks], bA, accA, 0, 0, 0);
                accB = __builtin_amdgcn_mfma_f32_16x16x32_f16(qfrag[ks], bB, accB, 0, 0, 0);
                accC = __builtin_amdgcn_mfma_f32_16x16x32_f16(qfrag[ks], bC, accC, 0, 0, 0);
                accD = __builtin_amdgcn_mfma_f32_16x16x32_f16(qfrag[ks], bD, accD, 0, 0, 0);
            }
            float4 kcv = *(float4*)&ktrc[keyb][0];
            float4 ksv = *(float4*)&ktrs[keyb][0];
            #pragma unroll
            for (int r = 0; r < 4; ++r) {
                float CC = qcv[r].x*kcv.x + qcv[r].y*kcv.y + qcv[r].z*kcv.z + qcv[r].w*kcv.w;
                float CS = qcv[r].x*ksv.x + qcv[r].y*ksv.y + qcv[r].z*ksv.z + qcv[r].w*ksv.w;
                float SC = qsv[r].x*kcv.x + qsv[r].y*kcv.y + qsv[r].z*kcv.z + qsv[r].w*kcv.w;
                float SS = qsv[r].x*ksv.x + qsv[r].y*ksv.y + qsv[r].z*ksv.z + qsv[r].w*ksv.w;
                sc[kt2][r] = (accA[r]*CC + accB[r]*CS + accC[r]*SC + accD[r]*SS) * (1.0f/32.0f);
            }
        }

        // ---- online softmax (row = wv*16 + quad*4 + r), write P fp16 ----
        #pragma unroll
        for (int r = 0; r < 4; ++r) {
            float tm = fmaxf(fmaxf(sc[0][r], sc[1][r]), fmaxf(sc[2][r], sc[3][r]));
            tm = fmaxf(tm, __shfl_xor(tm, 1));
            tm = fmaxf(tm, __shfl_xor(tm, 2));
            tm = fmaxf(tm, __shfl_xor(tm, 4));
            tm = fmaxf(tm, __shfl_xor(tm, 8));
            float mnew  = fmaxf(mrow[r], tm);
            float alpha = __expf(mrow[r] - mnew);
            int row = wv * 16 + quad * 4 + r;
            float psum = 0.f;
            #pragma unroll
            for (int kt2 = 0; kt2 < 4; ++kt2) {
                float p = __expf(sc[kt2][r] - mnew);
                psum += p;
                int key = kt2 * 16 + nn;
                int ch = ((key >> 3) ^ (row & 7));
                pss[row][ch * 8 + (key & 7)] = (_Float16)p;
            }
            psum += __shfl_xor(psum, 1);
            psum += __shfl_xor(psum, 2);
            psum += __shfl_xor(psum, 4);
            psum += __shfl_xor(psum, 8);
            lrow[r] = lrow[r] * alpha + psum;
            mrow[r] = mnew;
            Oacc[0][r] *= alpha; Oacc[1][r] *= alpha;
            Oacc[2][r] *= alpha; Oacc[3][r] *= alpha;
        }

        // ---- PV: O[16 rows x 64 e] += P x V  (wave-local P, no barrier) ----
        {
            int prow = wv * 16 + nn;
            #pragma unroll
            for (int ks = 0; ks < 2; ++ks) {
                int chp = ((quad + 4 * ks) ^ (prow & 7)) * 8;
                f16x8 pf = *(f16x8*)&pss[prow][chp];
                #pragma unroll
                for (int et = 0; et < 4; ++et) {
                    int e = et * 16 + nn;
                    int chv = ((quad + 4 * ks) ^ (e & 7)) * 8;
                    f16x8 vf = *(f16x8*)&vts[e][chv];
                    Oacc[et] = __builtin_amdgcn_mfma_f32_16x16x32_f16(pf, vf, Oacc[et], 0, 0, 0);
                }
            }
        }
        __syncthreads();   // protect k4s/vts/ktr before next staging
    }

    // ---- epilogue ----
    float* ob = out + ((size_t)((b * L_ + l0) * H_ + h)) * E_;
    #pragma unroll
    for (int r = 0; r < 4; ++r) {
        float inv = 1.0f / lrow[r];
        int row = wv * 16 + quad * 4 + r;
        #pragma unroll
        for (int et = 0; et < 4; ++et) {
            ob[(size_t)row * (H_ * E_) + et * 16 + nn] = Oacc[et][r] * inv;
        }
    }
}

extern "C" void kernel_launch(void* const* d_in, const int* in_sizes, int n_in,
                              void* d_out, int out_size, void* d_ws, size_t ws_size,
                              hipStream_t stream) {
    const float* qp = (const float*)d_in[0];
    const float* kp = (const float*)d_in[1];
    const float* vp = (const float*)d_in[2];
    const float* qo = (const float*)d_in[3];
    const float* qt = (const float*)d_in[4];
    const float* ko = (const float*)d_in[5];
    const float* kt = (const float*)d_in[6];
    float* out = (float*)d_out;

    dim3 grid(L_ / 64, H_, B_);
    qattn_mfma<<<grid, dim3(NTH), 0, stream>>>(qp, kp, vp, qo, qt, ko, kt, out);
}